// Round 11
// baseline (694.279 us; speedup 1.0000x reference)
//
#include <hip/hip_runtime.h>
#include <hip/hip_bf16.h>
#include <stdio.h>

// BNBQuantizedLinear: out = x @ dequant(w)^T + bias
// x [8192,4096] f32, w [11008,4096] f32 (group-128 affine fake-quant), out f32.
// Round 11: round-10 B-streaming with the k-slot bug fixed. The A-side LDS
// swizzle is an involution (write pre-XOR + read XOR cancel), so A fragments
// hold NATURAL k-group kg; round 10 XOR'd B's global address (no cancelling
// write side) -> k-mismatch -> absmax 488. Fix: B streams at natural kg*16.
// Rest identical: int8 MFMA (16x16x64), A via 4-ring LDS (64 KB) with
// source-pre-swizzled global_load_lds, B global->reg 1 tile ahead (ping-pong),
// counted vmcnt, 1 barrier/tile, bijective XCD swizzle, rank-1 mean
// correction + bias in epilogue.

typedef signed char i8;
typedef unsigned int u32;
typedef __attribute__((ext_vector_type(4))) int i32x4;

constexpr int Mdim = 8192;
constexpr int Ndim = 11008;
constexpr int Kdim = 4096;

#define NT64 64             // K tiles of 64
#define TEB 16384           // bytes per A K-tile buffer: 256 rows x 64 B

__device__ __forceinline__ int q_i8(float v, float mult) {
  float q = rintf(v * mult);
  q = fmaxf(-127.0f, fminf(127.0f, q));
  return (int)q;
}

// ---------------- kernel 1: weight -> residual int8 + row mean ----------------
__global__ __launch_bounds__(512) void k_prep_w(const float* __restrict__ w,
                                                i8* __restrict__ w8,
                                                float* __restrict__ mu) {
  const int o = blockIdx.x;
  const int t = threadIdx.x;
  const int g = t >> 4;
  __shared__ float s_sc[32], s_mn[32], s_gmu[32];
  __shared__ float s_mu;

  const float* wr = w + (size_t)o * Kdim + t * 8;
  const float4 v0 = *(const float4*)wr;
  const float4 v1 = *(const float4*)(wr + 4);
  float v[8] = {v0.x, v0.y, v0.z, v0.w, v1.x, v1.y, v1.z, v1.w};

  float mn = v[0], mx = v[0], sm = 0.0f;
#pragma unroll
  for (int j = 0; j < 8; ++j) {
    mn = fminf(mn, v[j]); mx = fmaxf(mx, v[j]); sm += v[j];
  }
#pragma unroll
  for (int off = 1; off < 16; off <<= 1) {
    mn = fminf(mn, __shfl_xor(mn, off));
    mx = fmaxf(mx, __shfl_xor(mx, off));
    sm += __shfl_xor(sm, off);
  }
  if ((t & 15) == 0) {
    const float sc = (mx - mn) * (1.0f / 15.0f);
    s_sc[g] = sc;
    s_mn[g] = mn;
    s_gmu[g] = sc * (sm * (1.0f / 128.0f)) + mn;
  }
  __syncthreads();
  if (t == 0) {
    float s = 0.0f;
#pragma unroll
    for (int c = 0; c < 32; ++c) s += s_gmu[c];
    s_mu = s * (1.0f / 32.0f);
    mu[o] = s_mu;
  }
  __syncthreads();
  const float sc = s_sc[g], mnv = s_mn[g], m = s_mu;
  const float mult = 127.0f / 4.5f;
  u32 lo = 0, hi = 0;
#pragma unroll
  for (int j = 0; j < 4; ++j) {
    const float wd = v[j] * sc + mnv;
    lo |= ((u32)(q_i8(wd - m, mult) & 0xff)) << (8 * j);
  }
#pragma unroll
  for (int j = 0; j < 4; ++j) {
    const float wd = v[4 + j] * sc + mnv;
    hi |= ((u32)(q_i8(wd - m, mult) & 0xff)) << (8 * j);
  }
  u32* dst = (u32*)(w8 + (size_t)o * Kdim + t * 8);
  dst[0] = lo; dst[1] = hi;
}

// ---------------- kernel 2: x -> int8 + exact f32 row sums ----------------
__global__ __launch_bounds__(512) void k_prep_x(const float* __restrict__ x,
                                                i8* __restrict__ x8,
                                                float* __restrict__ X) {
  const int m = blockIdx.x;
  const int t = threadIdx.x;
  __shared__ float s_ws[8];
  const float* xr = x + (size_t)m * Kdim + t * 8;
  const float4 v0 = *(const float4*)xr;
  const float4 v1 = *(const float4*)(xr + 4);
  float v[8] = {v0.x, v0.y, v0.z, v0.w, v1.x, v1.y, v1.z, v1.w};
  float sm = 0.0f;
#pragma unroll
  for (int j = 0; j < 8; ++j) sm += v[j];
  const float mult = 127.0f / 6.0f;
  u32 lo = 0, hi = 0;
#pragma unroll
  for (int j = 0; j < 4; ++j) lo |= ((u32)(q_i8(v[j], mult) & 0xff)) << (8 * j);
#pragma unroll
  for (int j = 0; j < 4; ++j) hi |= ((u32)(q_i8(v[4 + j], mult) & 0xff)) << (8 * j);
  u32* dst = (u32*)(x8 + (size_t)m * Kdim + t * 8);
  dst[0] = lo; dst[1] = hi;
#pragma unroll
  for (int off = 1; off < 64; off <<= 1) sm += __shfl_xor(sm, off);
  if ((t & 63) == 0) s_ws[t >> 6] = sm;
  __syncthreads();
  if (t == 0) {
    float s = 0.0f;
#pragma unroll
    for (int wv = 0; wv < 8; ++wv) s += s_ws[wv];
    X[m] = s;
  }
}

// ---------------- kernel 3: int8 GEMM, A via LDS, B streamed to regs ----------------
__device__ __forceinline__ void async_ld16(const i8* g, i8* l) {
  __builtin_amdgcn_global_load_lds(
      (const __attribute__((address_space(1))) void*)g,
      (__attribute__((address_space(3))) void*)l, 16, 0, 0);
}

__global__ __launch_bounds__(512, 2) void k_gemm(const i8* __restrict__ A,
                                                 const i8* __restrict__ B,
                                                 const float* __restrict__ bias,
                                                 const float* __restrict__ mu,
                                                 const float* __restrict__ X,
                                                 float* __restrict__ C) {
  __shared__ i8 As[4 * TEB];   // 64 KB: 4-ring of A K-tiles [256 rows][64 B]

  const int t = threadIdx.x;
  const int wave = t >> 6;        // 0..7
  const int lane = t & 63;
  const int wm = wave >> 2;       // 2(M) x 4(N); wave owns 128x64 out
  const int wn = wave & 3;
  const int r  = lane & 15;
  const int kg = lane >> 4;       // K-group: 16 i8 each (K=64 total)
  const int slot = kg ^ ((r >> 1) & 3);   // A LDS-read swizzle (involution
                                          // with the staging pre-XOR -> A frag
                                          // holds NATURAL k-group kg)

  // bijective XCD swizzle: 1376 workgroups = 8 XCDs x 172
  const int bid = blockIdx.x;
  const int wg = (bid & 7) * 172 + (bid >> 3);
  const int by = wg / 43;
  const int bx = wg % 43;
  const long bm0 = (long)by * 256;
  const long bn0 = (long)bx * 256;

  // A staging: one issue = 512 thr x 16B = 8 KB = 128 rows x 64 B; 2 per tile.
  const int s_row  = t >> 2;
  const int s_slot = (t & 3) ^ ((t >> 3) & 3);
  const i8* a_src = A + (bm0 + s_row) * Kdim + s_slot * 16;
  const int st_off = wave * 1024;

  const int a_roff = (wm * 128 + r) * 64 + slot * 16;  // bytes; + mf*1024

  // B fragment stream at NATURAL k-slot kg (bugfix vs round 10):
  // lane reads B[bn0 + wn*64 + nf*16 + r][tau*64 + kg*16]
  const i8* b_frag = B + (bn0 + wn * 64 + r) * (size_t)Kdim + kg * 16;

  i32x4 acc[8][4] = {};
  i32x4 bsA[4], bsB[4];   // B reg sets, ping-pong by tile parity

#define STAGE_A(TAU, BUF) do {                                    \
    const i8* ga_ = a_src + (size_t)(TAU) * 64;                   \
    i8* la_ = As + (BUF) * TEB + st_off;                          \
    async_ld16(ga_,                       la_);                   \
    async_ld16(ga_ + (size_t)128 * Kdim,  la_ + 8192);            \
  } while (0)

#define LOADB(TAU, DST) do {                                      \
    const i8* gb_ = b_frag + (size_t)(TAU) * 64;                  \
    _Pragma("unroll")                                             \
    for (int nf = 0; nf < 4; ++nf)                                \
      DST[nf] = *(const i32x4*)(gb_ + (size_t)nf * 16 * Kdim);    \
  } while (0)

#define VM6 asm volatile("s_waitcnt vmcnt(6)" ::: "memory")
#define VM4 asm volatile("s_waitcnt vmcnt(4)" ::: "memory")
#define VMNONE (void)0

  // Hazard ledger (A 2 loads/tile staged 3 ahead; B 4 reg-loads 1 ahead):
  //  RAW cross-wave: tile t reads buf t&3 staged at t-3. B(t-2) was issued at
  //  tile t-3 AFTER A(t)'s stage; MFMA(t-2) consumes B(t-2) -> compiler wait
  //  -> in-order retirement drains A(t) per-wave by mid-tile t-2; barriers
  //  (t-2,t-1) publish to all waves before tile t's ds_reads. Safe.
  //  WAR: STAGE_A(t+3) -> ring slot (t-1)&3; its reads finished before
  //  barrier(t-1), stage issued after. B reg ping-pong compiler-tracked.
  //  Steady outstanding after MFMAs: A(t+3):2 + B(t+1):4 = 6 -> VM6 no-op
  //  (insurance), barrier does the cross-wave publish.
#define KTILE(TAU, BUF, BCUR, BLD, DO_STAGE, DO_LOAD, VMSTMT) do {           \
    if (DO_STAGE) STAGE_A((TAU) + 3, ((BUF) + 3) & 3);                       \
    if (DO_LOAD) LOADB((TAU) + 1, BLD);                                      \
    const i8* Ab_ = As + (BUF) * TEB;                                        \
    i32x4 af[8];                                                             \
    _Pragma("unroll")                                                        \
    for (int mf = 0; mf < 8; ++mf) af[mf] = *(const i32x4*)(Ab_ + a_roff + mf * 1024); \
    __builtin_amdgcn_s_setprio(1);                                           \
    _Pragma("unroll")                                                        \
    for (int mf = 0; mf < 8; ++mf)                                           \
      _Pragma("unroll")                                                      \
      for (int nf = 0; nf < 4; ++nf)                                         \
        acc[mf][nf] = __builtin_amdgcn_mfma_i32_16x16x64_i8(af[mf], BCUR[nf], acc[mf][nf], 0, 0, 0); \
    __builtin_amdgcn_s_setprio(0);                                           \
    VMSTMT;                                                                  \
    __builtin_amdgcn_s_barrier();                                            \
  } while (0)

  // prologue: A tiles 0,1,2 staged; B tile 0 into bsA.
  STAGE_A(0, 0);
  LOADB(0, bsA);
  STAGE_A(1, 1);
  STAGE_A(2, 2);
  VM4;                     // order [A0:2, B0:4, A1:2, A2:2] -> drains A0+B0
  __builtin_amdgcn_s_barrier();

  for (int tau = 0; tau < NT64 - 4; tau += 4) {
    KTILE(tau + 0, 0, bsA, bsB, 1, 1, VM6);
    KTILE(tau + 1, 1, bsB, bsA, 1, 1, VM6);
    KTILE(tau + 2, 2, bsA, bsB, 1, 1, VM6);
    KTILE(tau + 3, 3, bsB, bsA, 1, 1, VM6);
  }
  KTILE(60, 0, bsA, bsB, 1, 1, VM6);   // stages A63, loads B61
  KTILE(61, 1, bsB, bsA, 0, 1, VM4);   // loads B62; VM4 drains A63
  KTILE(62, 2, bsA, bsB, 0, 1, VMNONE);   // loads B63
  KTILE(63, 3, bsB, bsA, 0, 0, VMNONE);

  // epilogue: C/D layout col = lane&15, row = (lane>>4)*4 + j
  const float sxsw = (6.0f / 127.0f) * (4.5f / 127.0f);
#pragma unroll
  for (int nf = 0; nf < 4; ++nf) {
    const long col = bn0 + wn * 64 + nf * 16 + r;
    const float bv = bias[col];
    const float mv = mu[col];
#pragma unroll
    for (int mf = 0; mf < 8; ++mf) {
      const long row0 = bm0 + wm * 128 + mf * 16 + kg * 4;
#pragma unroll
      for (int j = 0; j < 4; ++j) {
        const long row = row0 + j;
        C[row * Ndim + col] = sxsw * (float)acc[mf][nf][j] + mv * X[row] + bv;
      }
    }
  }
}

extern "C" void kernel_launch(void* const* d_in, const int* in_sizes, int n_in,
                              void* d_out, int out_size, void* d_ws, size_t ws_size,
                              hipStream_t stream) {
  const float* x    = (const float*)d_in[0];
  const float* w    = (const float*)d_in[1];
  const float* bias = (const float*)d_in[2];
  float* out = (float*)d_out;

  const size_t xb_bytes = (size_t)Mdim * Kdim;
  const size_t wb_bytes = (size_t)Ndim * Kdim;
  const size_t off_X  = xb_bytes + wb_bytes;
  const size_t off_mu = off_X + (size_t)Mdim * 4;
  const size_t need   = off_mu + (size_t)Ndim * 4;
  if (ws_size < need) {
    fprintf(stderr, "kernel_launch: ws too small (%zu < %zu)\n", ws_size, need);
    return;
  }
  i8* xb8 = (i8*)d_ws;
  i8* wb8 = xb8 + xb_bytes;
  float* Xs = (float*)((char*)d_ws + off_X);
  float* muW = (float*)((char*)d_ws + off_mu);

  k_prep_w<<<Ndim, 512, 0, stream>>>(w, wb8, muW);
  k_prep_x<<<Mdim, 512, 0, stream>>>(x, xb8, Xs);

  // grid: 43 N-tiles x 32 M-tiles = 1376 blocks (divisible by 8 XCDs)
  k_gemm<<<(Ndim / 256) * (Mdim / 256), 512, 0, stream>>>(xb8, wb8, bias, muW, Xs, out);
}

// Round 12
// 528.124 us; speedup vs baseline: 1.3146x; 1.3146x over previous
//
#include <hip/hip_runtime.h>
#include <hip/hip_bf16.h>
#include <stdio.h>

// BNBQuantizedLinear: out = x @ dequant(w)^T + bias
// x [8192,4096] f32, w [11008,4096] f32 (group-128 affine fake-quant), out f32.
// Round 12: B streamed to registers from a FRAGMENT-MAJOR layout (round 11's
// gather -> coalesced 1KB wave-loads). k_prep_w writes quantized weights as
// B'[(nb*64+tau)*1024 + (kg*16+r)*16] (nb = 16-row n-block, tau = K64 tile,
// lane = kg*16+r), so LOADB is 4x coalesced 1KB reads/tile. A-path byte-
// identical to proven round 9 (455us): 4-ring LDS, source-pre-swizzled
// global_load_lds, natural-k involution. LDS 64KB -> 2 blocks/CU. Ledger:
// in-order VMEM retirement means the compiler's wait for B(t) (register dep,
// issued after A(t+2)'s stage) drains A(t+1)/A(t+2) before each wave's MFMAs
// and barrier; explicit vmcnt only in prologue.

typedef signed char i8;
typedef unsigned int u32;
typedef unsigned long long u64;
typedef __attribute__((ext_vector_type(4))) int i32x4;

constexpr int Mdim = 8192;
constexpr int Ndim = 11008;
constexpr int Kdim = 4096;

#define NT64 64             // K tiles of 64
#define TEB 16384           // bytes per A K-tile buffer: 256 rows x 64 B

__device__ __forceinline__ int q_i8(float v, float mult) {
  float q = rintf(v * mult);
  q = fmaxf(-127.0f, fminf(127.0f, q));
  return (int)q;
}

// ---------------- kernel 1: weight -> residual int8 (fragment-major) + row mean ----------------
// One block per output row o; 512 thr x 8 elems. Quant math identical to
// round 9 (verified absmax 6.0); only the WRITE address is fragment-major:
// thread t holds elems k=t*8..t*8+7 = half of 16B-slot s=t>>1 (tau=t>>3,
// kg=(t>>1)&3); dest = ((o>>4)*64 + tau)*1024 + (kg*16 + (o&15))*16 + (t&1)*8.
__global__ __launch_bounds__(512) void k_prep_w(const float* __restrict__ w,
                                                i8* __restrict__ w8,
                                                float* __restrict__ mu) {
  const int o = blockIdx.x;
  const int t = threadIdx.x;
  const int g = t >> 4;
  __shared__ float s_sc[32], s_mn[32], s_gmu[32];
  __shared__ float s_mu;

  const float* wr = w + (size_t)o * Kdim + t * 8;
  const float4 v0 = *(const float4*)wr;
  const float4 v1 = *(const float4*)(wr + 4);
  float v[8] = {v0.x, v0.y, v0.z, v0.w, v1.x, v1.y, v1.z, v1.w};

  float mn = v[0], mx = v[0], sm = 0.0f;
#pragma unroll
  for (int j = 0; j < 8; ++j) {
    mn = fminf(mn, v[j]); mx = fmaxf(mx, v[j]); sm += v[j];
  }
#pragma unroll
  for (int off = 1; off < 16; off <<= 1) {
    mn = fminf(mn, __shfl_xor(mn, off));
    mx = fmaxf(mx, __shfl_xor(mx, off));
    sm += __shfl_xor(sm, off);
  }
  if ((t & 15) == 0) {
    const float sc = (mx - mn) * (1.0f / 15.0f);
    s_sc[g] = sc;
    s_mn[g] = mn;
    s_gmu[g] = sc * (sm * (1.0f / 128.0f)) + mn;
  }
  __syncthreads();
  if (t == 0) {
    float s = 0.0f;
#pragma unroll
    for (int c = 0; c < 32; ++c) s += s_gmu[c];
    s_mu = s * (1.0f / 32.0f);
    mu[o] = s_mu;
  }
  __syncthreads();
  const float sc = s_sc[g], mnv = s_mn[g], m = s_mu;
  const float mult = 127.0f / 4.5f;
  u32 lo = 0, hi = 0;
#pragma unroll
  for (int j = 0; j < 4; ++j) {
    const float wd = v[j] * sc + mnv;
    lo |= ((u32)(q_i8(wd - m, mult) & 0xff)) << (8 * j);
  }
#pragma unroll
  for (int j = 0; j < 4; ++j) {
    const float wd = v[4 + j] * sc + mnv;
    hi |= ((u32)(q_i8(wd - m, mult) & 0xff)) << (8 * j);
  }
  const size_t dst = ((size_t)(o >> 4) * 64 + (t >> 3)) * 1024
                   + (size_t)(((t >> 1) & 3) * 16 + (o & 15)) * 16
                   + (size_t)(t & 1) * 8;
  *(u64*)(w8 + dst) = (u64)lo | ((u64)hi << 32);
}

// ---------------- kernel 2: x -> int8 + exact f32 row sums ----------------
__global__ __launch_bounds__(512) void k_prep_x(const float* __restrict__ x,
                                                i8* __restrict__ x8,
                                                float* __restrict__ X) {
  const int m = blockIdx.x;
  const int t = threadIdx.x;
  __shared__ float s_ws[8];
  const float* xr = x + (size_t)m * Kdim + t * 8;
  const float4 v0 = *(const float4*)xr;
  const float4 v1 = *(const float4*)(xr + 4);
  float v[8] = {v0.x, v0.y, v0.z, v0.w, v1.x, v1.y, v1.z, v1.w};
  float sm = 0.0f;
#pragma unroll
  for (int j = 0; j < 8; ++j) sm += v[j];
  const float mult = 127.0f / 6.0f;
  u32 lo = 0, hi = 0;
#pragma unroll
  for (int j = 0; j < 4; ++j) lo |= ((u32)(q_i8(v[j], mult) & 0xff)) << (8 * j);
#pragma unroll
  for (int j = 0; j < 4; ++j) hi |= ((u32)(q_i8(v[4 + j], mult) & 0xff)) << (8 * j);
  u32* dst = (u32*)(x8 + (size_t)m * Kdim + t * 8);
  dst[0] = lo; dst[1] = hi;
#pragma unroll
  for (int off = 1; off < 64; off <<= 1) sm += __shfl_xor(sm, off);
  if ((t & 63) == 0) s_ws[t >> 6] = sm;
  __syncthreads();
  if (t == 0) {
    float s = 0.0f;
#pragma unroll
    for (int wv = 0; wv < 8; ++wv) s += s_ws[wv];
    X[m] = s;
  }
}

// ---------------- kernel 3: int8 GEMM, A via LDS ring, B' streamed coalesced ----------------
__device__ __forceinline__ void async_ld16(const i8* g, i8* l) {
  __builtin_amdgcn_global_load_lds(
      (const __attribute__((address_space(1))) void*)g,
      (__attribute__((address_space(3))) void*)l, 16, 0, 0);
}

__global__ __launch_bounds__(512, 2) void k_gemm(const i8* __restrict__ A,
                                                 const i8* __restrict__ Bp,
                                                 const float* __restrict__ bias,
                                                 const float* __restrict__ mu,
                                                 const float* __restrict__ X,
                                                 float* __restrict__ C) {
  __shared__ i8 As[4 * TEB];   // 64 KB: 4-ring of A K-tiles [256 rows][64 B]

  const int t = threadIdx.x;
  const int wave = t >> 6;        // 0..7
  const int lane = t & 63;
  const int wm = wave >> 2;       // 2(M) x 4(N); wave owns 128x64 out
  const int wn = wave & 3;
  const int r  = lane & 15;
  const int kg = lane >> 4;       // K-group: 16 i8 each (K=64 total)
  const int slot = kg ^ ((r >> 1) & 3);   // A LDS-read swizzle (involution with
                                          // staging pre-XOR -> natural k)

  // bijective XCD swizzle: 1376 workgroups = 8 XCDs x 172
  const int bid = blockIdx.x;
  const int wg = (bid & 7) * 172 + (bid >> 3);
  const int by = wg / 43;
  const int bx = wg % 43;
  const long bm0 = (long)by * 256;
  const long bn0 = (long)bx * 256;

  // A staging: one issue = 512 thr x 16B = 8 KB = 128 rows x 64 B; 2 per tile.
  const int s_row  = t >> 2;
  const int s_slot = (t & 3) ^ ((t >> 3) & 3);
  const i8* a_src = A + (bm0 + s_row) * Kdim + s_slot * 16;
  const int st_off = wave * 1024;

  const int a_roff = (wm * 128 + r) * 64 + slot * 16;  // bytes; + mf*1024

  // B' fragment stream (fragment-major, coalesced): wave's nf-block nb =
  // bx*16 + wn*4 + nf; lane reads 16B at (nb*64+tau)*1024 + lane*16.
  const i8* b_frag = Bp + ((size_t)bx * 16 + wn * 4) * 65536 + (size_t)lane * 16;

  i32x4 acc[8][4] = {};
  i32x4 bsA[4], bsB[4];   // B reg sets, ping-pong by tile parity

#define STAGE_A(TAU, BUF) do {                                    \
    const i8* ga_ = a_src + (size_t)(TAU) * 64;                   \
    i8* la_ = As + (BUF) * TEB + st_off;                          \
    async_ld16(ga_,                       la_);                   \
    async_ld16(ga_ + (size_t)128 * Kdim,  la_ + 8192);            \
  } while (0)

#define LOADB(TAU, DST) do {                                      \
    const i8* gb_ = b_frag + (size_t)(TAU) * 1024;                \
    _Pragma("unroll")                                             \
    for (int nf = 0; nf < 4; ++nf)                                \
      DST[nf] = *(const i32x4*)(gb_ + (size_t)nf * 65536);        \
  } while (0)

#define VM8 asm volatile("s_waitcnt vmcnt(8)" ::: "memory")
#define VMNONE (void)0

  // Hazard ledger:
  //  Per tile issue order: [A(t+3):2 gload_lds, B(t+1):4 reg-loads].
  //  MFMA(t) consumes B(t) (issued tile t-1, AFTER A(t+2)'s stage) -> compiler
  //  emits the vmcnt wait for B(t); in-order VMEM retirement then guarantees
  //  A(t+1) and A(t+2) are drained per-wave BEFORE the MFMAs, hence before
  //  barrier(t) -> tile t+1's ds_reads are safe on all waves. No explicit
  //  vmcnt needed in the steady loop.
  //  WAR: STAGE_A(t+3) -> ring slot (t-1)&3; its ds_reads completed before
  //  barrier(t-1) (consumed by MFMAs pre-barrier), stage issued after.
  //  B reg ping-pong WAR is compiler-tracked (register dependence).
#define KTILE(TAU, BUF, BCUR, BLD, DO_STAGE, DO_LOAD) do {                   \
    if (DO_STAGE) STAGE_A((TAU) + 3, ((BUF) + 3) & 3);                       \
    if (DO_LOAD) LOADB((TAU) + 1, BLD);                                      \
    const i8* Ab_ = As + (BUF) * TEB;                                        \
    i32x4 af[8];                                                             \
    _Pragma("unroll")                                                        \
    for (int mf = 0; mf < 8; ++mf) af[mf] = *(const i32x4*)(Ab_ + a_roff + mf * 1024); \
    __builtin_amdgcn_s_setprio(1);                                           \
    _Pragma("unroll")                                                        \
    for (int mf = 0; mf < 8; ++mf)                                           \
      _Pragma("unroll")                                                      \
      for (int nf = 0; nf < 4; ++nf)                                         \
        acc[mf][nf] = __builtin_amdgcn_mfma_i32_16x16x64_i8(af[mf], BCUR[nf], acc[mf][nf], 0, 0, 0); \
    __builtin_amdgcn_s_setprio(0);                                           \
    __builtin_amdgcn_s_barrier();                                            \
  } while (0)

  // prologue: A tiles 0,1,2 staged; B tile 0 into bsA.
  STAGE_A(0, 0);          // oldest
  STAGE_A(1, 1);
  STAGE_A(2, 2);
  LOADB(0, bsA);
  VM8;                    // outstanding [A0:2,A1:2,A2:2,B0:4]=10 -> drain A0
  __builtin_amdgcn_s_barrier();

  for (int tau = 0; tau < NT64 - 4; tau += 4) {
    KTILE(tau + 0, 0, bsA, bsB, 1, 1);
    KTILE(tau + 1, 1, bsB, bsA, 1, 1);
    KTILE(tau + 2, 2, bsA, bsB, 1, 1);
    KTILE(tau + 3, 3, bsB, bsA, 1, 1);
  }
  KTILE(60, 0, bsA, bsB, 1, 1);   // stages A63, loads B61
  KTILE(61, 1, bsB, bsA, 0, 1);   // loads B62 (B62 wait @62 drains A63)
  KTILE(62, 2, bsA, bsB, 0, 1);   // loads B63
  KTILE(63, 3, bsB, bsA, 0, 0);

  // epilogue: C/D layout col = lane&15, row = (lane>>4)*4 + j
  const float sxsw = (6.0f / 127.0f) * (4.5f / 127.0f);
#pragma unroll
  for (int nf = 0; nf < 4; ++nf) {
    const long col = bn0 + wn * 64 + nf * 16 + r;
    const float bv = bias[col];
    const float mv = mu[col];
#pragma unroll
    for (int mf = 0; mf < 8; ++mf) {
      const long row0 = bm0 + wm * 128 + mf * 16 + kg * 4;
#pragma unroll
      for (int j = 0; j < 4; ++j) {
        const long row = row0 + j;
        C[row * Ndim + col] = sxsw * (float)acc[mf][nf][j] + mv * X[row] + bv;
      }
    }
  }
}

extern "C" void kernel_launch(void* const* d_in, const int* in_sizes, int n_in,
                              void* d_out, int out_size, void* d_ws, size_t ws_size,
                              hipStream_t stream) {
  const float* x    = (const float*)d_in[0];
  const float* w    = (const float*)d_in[1];
  const float* bias = (const float*)d_in[2];
  float* out = (float*)d_out;

  const size_t xb_bytes = (size_t)Mdim * Kdim;
  const size_t wb_bytes = (size_t)Ndim * Kdim;   // B' same size, fragment-major
  const size_t off_X  = xb_bytes + wb_bytes;
  const size_t off_mu = off_X + (size_t)Mdim * 4;
  const size_t need   = off_mu + (size_t)Ndim * 4;
  if (ws_size < need) {
    fprintf(stderr, "kernel_launch: ws too small (%zu < %zu)\n", ws_size, need);
    return;
  }
  i8* xb8 = (i8*)d_ws;
  i8* wb8 = xb8 + xb_bytes;
  float* Xs = (float*)((char*)d_ws + off_X);
  float* muW = (float*)((char*)d_ws + off_mu);

  k_prep_w<<<Ndim, 512, 0, stream>>>(w, wb8, muW);
  k_prep_x<<<Mdim, 512, 0, stream>>>(x, xb8, Xs);

  // grid: 43 N-tiles x 32 M-tiles = 1376 blocks (divisible by 8 XCDs)
  k_gemm<<<(Ndim / 256) * (Mdim / 256), 512, 0, stream>>>(xb8, wb8, bias, muW, Xs, out);
}

// Round 13
// 493.327 us; speedup vs baseline: 1.4073x; 1.0705x over previous
//
#include <hip/hip_runtime.h>
#include <hip/hip_bf16.h>
#include <stdio.h>

// BNBQuantizedLinear: out = x @ dequant(w)^T + bias
// x [8192,4096] f32, w [11008,4096] f32 (group-128 affine fake-quant), out f32.
// Round 13: round-12 GEMM (int8 MFMA, A via 4-ring LDS, fragment-major B'
// streamed to regs) + COALESCED EPILOGUE. The raw 16x16 C/D layout stores
// 4rows x 16cols = 64B chunks (half L2 lines; WRITE_SIZE 458MB vs 360 ideal).
// After the final barrier As is dead (64KB = 8KB/wave): 4 passes of 32x64 f32
// per wave -> fold corrections, ds_write_b32 with col ^ 16*((row>>2)&3)
// swizzle (2 lanes/bank write, GEMM-read-equivalent read density), read back
// float4, 32 fully-coalesced global_store_dwordx4 per wave (4 x 256B rows per
// instruction) instead of 128 half-line scalar stores.

typedef signed char i8;
typedef unsigned int u32;
typedef unsigned long long u64;
typedef __attribute__((ext_vector_type(4))) int i32x4;
typedef __attribute__((ext_vector_type(4))) float f32x4;

constexpr int Mdim = 8192;
constexpr int Ndim = 11008;
constexpr int Kdim = 4096;

#define NT64 64             // K tiles of 64
#define TEB 16384           // bytes per A K-tile buffer: 256 rows x 64 B

__device__ __forceinline__ int q_i8(float v, float mult) {
  float q = rintf(v * mult);
  q = fmaxf(-127.0f, fminf(127.0f, q));
  return (int)q;
}

// ---------------- kernel 1: weight -> residual int8 (fragment-major) + row mean ----------------
__global__ __launch_bounds__(512) void k_prep_w(const float* __restrict__ w,
                                                i8* __restrict__ w8,
                                                float* __restrict__ mu) {
  const int o = blockIdx.x;
  const int t = threadIdx.x;
  const int g = t >> 4;
  __shared__ float s_sc[32], s_mn[32], s_gmu[32];
  __shared__ float s_mu;

  const float* wr = w + (size_t)o * Kdim + t * 8;
  const float4 v0 = *(const float4*)wr;
  const float4 v1 = *(const float4*)(wr + 4);
  float v[8] = {v0.x, v0.y, v0.z, v0.w, v1.x, v1.y, v1.z, v1.w};

  float mn = v[0], mx = v[0], sm = 0.0f;
#pragma unroll
  for (int j = 0; j < 8; ++j) {
    mn = fminf(mn, v[j]); mx = fmaxf(mx, v[j]); sm += v[j];
  }
#pragma unroll
  for (int off = 1; off < 16; off <<= 1) {
    mn = fminf(mn, __shfl_xor(mn, off));
    mx = fmaxf(mx, __shfl_xor(mx, off));
    sm += __shfl_xor(sm, off);
  }
  if ((t & 15) == 0) {
    const float sc = (mx - mn) * (1.0f / 15.0f);
    s_sc[g] = sc;
    s_mn[g] = mn;
    s_gmu[g] = sc * (sm * (1.0f / 128.0f)) + mn;
  }
  __syncthreads();
  if (t == 0) {
    float s = 0.0f;
#pragma unroll
    for (int c = 0; c < 32; ++c) s += s_gmu[c];
    s_mu = s * (1.0f / 32.0f);
    mu[o] = s_mu;
  }
  __syncthreads();
  const float sc = s_sc[g], mnv = s_mn[g], m = s_mu;
  const float mult = 127.0f / 4.5f;
  u32 lo = 0, hi = 0;
#pragma unroll
  for (int j = 0; j < 4; ++j) {
    const float wd = v[j] * sc + mnv;
    lo |= ((u32)(q_i8(wd - m, mult) & 0xff)) << (8 * j);
  }
#pragma unroll
  for (int j = 0; j < 4; ++j) {
    const float wd = v[4 + j] * sc + mnv;
    hi |= ((u32)(q_i8(wd - m, mult) & 0xff)) << (8 * j);
  }
  const size_t dst = ((size_t)(o >> 4) * 64 + (t >> 3)) * 1024
                   + (size_t)(((t >> 1) & 3) * 16 + (o & 15)) * 16
                   + (size_t)(t & 1) * 8;
  *(u64*)(w8 + dst) = (u64)lo | ((u64)hi << 32);
}

// ---------------- kernel 2: x -> int8 + exact f32 row sums ----------------
__global__ __launch_bounds__(512) void k_prep_x(const float* __restrict__ x,
                                                i8* __restrict__ x8,
                                                float* __restrict__ X) {
  const int m = blockIdx.x;
  const int t = threadIdx.x;
  __shared__ float s_ws[8];
  const float* xr = x + (size_t)m * Kdim + t * 8;
  const float4 v0 = *(const float4*)xr;
  const float4 v1 = *(const float4*)(xr + 4);
  float v[8] = {v0.x, v0.y, v0.z, v0.w, v1.x, v1.y, v1.z, v1.w};
  float sm = 0.0f;
#pragma unroll
  for (int j = 0; j < 8; ++j) sm += v[j];
  const float mult = 127.0f / 6.0f;
  u32 lo = 0, hi = 0;
#pragma unroll
  for (int j = 0; j < 4; ++j) lo |= ((u32)(q_i8(v[j], mult) & 0xff)) << (8 * j);
#pragma unroll
  for (int j = 0; j < 4; ++j) hi |= ((u32)(q_i8(v[4 + j], mult) & 0xff)) << (8 * j);
  u32* dst = (u32*)(x8 + (size_t)m * Kdim + t * 8);
  dst[0] = lo; dst[1] = hi;
#pragma unroll
  for (int off = 1; off < 64; off <<= 1) sm += __shfl_xor(sm, off);
  if ((t & 63) == 0) s_ws[t >> 6] = sm;
  __syncthreads();
  if (t == 0) {
    float s = 0.0f;
#pragma unroll
    for (int wv = 0; wv < 8; ++wv) s += s_ws[wv];
    X[m] = s;
  }
}

// ---------------- kernel 3: int8 GEMM, A via LDS ring, B' streamed, coalesced epilogue ----------------
__device__ __forceinline__ void async_ld16(const i8* g, i8* l) {
  __builtin_amdgcn_global_load_lds(
      (const __attribute__((address_space(1))) void*)g,
      (__attribute__((address_space(3))) void*)l, 16, 0, 0);
}

__global__ __launch_bounds__(512, 2) void k_gemm(const i8* __restrict__ A,
                                                 const i8* __restrict__ Bp,
                                                 const float* __restrict__ bias,
                                                 const float* __restrict__ mu,
                                                 const float* __restrict__ X,
                                                 float* __restrict__ C) {
  __shared__ i8 As[4 * TEB];   // 64 KB: 4-ring of A K-tiles; reused by epilogue

  const int t = threadIdx.x;
  const int wave = t >> 6;        // 0..7
  const int lane = t & 63;
  const int wm = wave >> 2;       // 2(M) x 4(N); wave owns 128x64 out
  const int wn = wave & 3;
  const int r  = lane & 15;
  const int kg = lane >> 4;       // K-group: 16 i8 each (K=64 total)
  const int slot = kg ^ ((r >> 1) & 3);   // A LDS-read swizzle (involution with
                                          // staging pre-XOR -> natural k)

  // bijective XCD swizzle: 1376 workgroups = 8 XCDs x 172
  const int bid = blockIdx.x;
  const int wg = (bid & 7) * 172 + (bid >> 3);
  const int by = wg / 43;
  const int bx = wg % 43;
  const long bm0 = (long)by * 256;
  const long bn0 = (long)bx * 256;

  // A staging: one issue = 512 thr x 16B = 8 KB = 128 rows x 64 B; 2 per tile.
  const int s_row  = t >> 2;
  const int s_slot = (t & 3) ^ ((t >> 3) & 3);
  const i8* a_src = A + (bm0 + s_row) * Kdim + s_slot * 16;
  const int st_off = wave * 1024;

  const int a_roff = (wm * 128 + r) * 64 + slot * 16;  // bytes; + mf*1024

  // B' fragment stream (fragment-major, coalesced)
  const i8* b_frag = Bp + ((size_t)bx * 16 + wn * 4) * 65536 + (size_t)lane * 16;

  i32x4 acc[8][4] = {};
  i32x4 bsA[4], bsB[4];   // B reg sets, ping-pong by tile parity

#define STAGE_A(TAU, BUF) do {                                    \
    const i8* ga_ = a_src + (size_t)(TAU) * 64;                   \
    i8* la_ = As + (BUF) * TEB + st_off;                          \
    async_ld16(ga_,                       la_);                   \
    async_ld16(ga_ + (size_t)128 * Kdim,  la_ + 8192);            \
  } while (0)

#define LOADB(TAU, DST) do {                                      \
    const i8* gb_ = b_frag + (size_t)(TAU) * 1024;                \
    _Pragma("unroll")                                             \
    for (int nf = 0; nf < 4; ++nf)                                \
      DST[nf] = *(const i32x4*)(gb_ + (size_t)nf * 65536);        \
  } while (0)

#define VM8 asm volatile("s_waitcnt vmcnt(8)" ::: "memory")
#define VMNONE (void)0

  // Hazard ledger: identical to round 12 (verified passing).
#define KTILE(TAU, BUF, BCUR, BLD, DO_STAGE, DO_LOAD) do {                   \
    if (DO_STAGE) STAGE_A((TAU) + 3, ((BUF) + 3) & 3);                       \
    if (DO_LOAD) LOADB((TAU) + 1, BLD);                                      \
    const i8* Ab_ = As + (BUF) * TEB;                                        \
    i32x4 af[8];                                                             \
    _Pragma("unroll")                                                        \
    for (int mf = 0; mf < 8; ++mf) af[mf] = *(const i32x4*)(Ab_ + a_roff + mf * 1024); \
    __builtin_amdgcn_s_setprio(1);                                           \
    _Pragma("unroll")                                                        \
    for (int mf = 0; mf < 8; ++mf)                                           \
      _Pragma("unroll")                                                      \
      for (int nf = 0; nf < 4; ++nf)                                         \
        acc[mf][nf] = __builtin_amdgcn_mfma_i32_16x16x64_i8(af[mf], BCUR[nf], acc[mf][nf], 0, 0, 0); \
    __builtin_amdgcn_s_setprio(0);                                           \
    __builtin_amdgcn_s_barrier();                                            \
  } while (0)

  // prologue: A tiles 0,1,2 staged; B tile 0 into bsA.
  STAGE_A(0, 0);
  STAGE_A(1, 1);
  STAGE_A(2, 2);
  LOADB(0, bsA);
  VM8;                    // outstanding [A0:2,A1:2,A2:2,B0:4]=10 -> drain A0
  __builtin_amdgcn_s_barrier();

  for (int tau = 0; tau < NT64 - 4; tau += 4) {
    KTILE(tau + 0, 0, bsA, bsB, 1, 1);
    KTILE(tau + 1, 1, bsB, bsA, 1, 1);
    KTILE(tau + 2, 2, bsA, bsB, 1, 1);
    KTILE(tau + 3, 3, bsB, bsA, 1, 1);
  }
  KTILE(60, 0, bsA, bsB, 1, 1);   // stages A63, loads B61
  KTILE(61, 1, bsB, bsA, 0, 1);   // loads B62 (B62 wait @62 drains A63)
  KTILE(62, 2, bsA, bsB, 0, 1);   // loads B63
  KTILE(63, 3, bsB, bsA, 0, 0);
  // final barrier passed: all waves' ds_reads of As are complete -> As is free.

  // ---- coalesced epilogue: per-wave LDS transpose, 4 passes of 32x64 f32 ----
  // C/D layout: lane (kg,r) holds acc[mf][nf][j] = C(mf*16+kg*4+j, nf*16+r)
  // within the wave's 128x64 block. Swizzle: col' = col ^ 16*((row>>2)&3);
  // writer's (row>>2)&3 == kg, reader's == (i&3) for rows 4i..4i+3 -> cancels.
  float* lds_f = (float*)As;                 // 8 KB = 2048 f32 per wave
  float* wls = lds_f + wave * 2048;
  const float sxsw = (6.0f / 127.0f) * (4.5f / 127.0f);
  float bv[4], mv[4];
#pragma unroll
  for (int nf = 0; nf < 4; ++nf) {
    const long col = bn0 + wn * 64 + nf * 16 + r;
    bv[nf] = bias[col];
    mv[nf] = mu[col];
  }
  const long crow0 = bm0 + wm * 128;
  const long ccol0 = bn0 + wn * 64;
#pragma unroll
  for (int p = 0; p < 4; ++p) {
#pragma unroll
    for (int mh = 0; mh < 2; ++mh) {
      const int mf = 2 * p + mh;
      const long rowg0 = crow0 + mf * 16 + kg * 4;
      float xv[4];
#pragma unroll
      for (int j = 0; j < 4; ++j) xv[j] = X[rowg0 + j];
#pragma unroll
      for (int nf = 0; nf < 4; ++nf) {
        const int c = nf * 16 + r;
        const int lr0 = mh * 16 + kg * 4;       // local row base (swz = 16*kg)
#pragma unroll
        for (int j = 0; j < 4; ++j) {
          const float val = sxsw * (float)acc[mf][nf][j] + mv[nf] * xv[j] + bv[nf];
          wls[(lr0 + j) * 64 + (c ^ (kg * 16))] = val;
        }
      }
    }
    // read back float4 (swz uniform per instr: 16*(i&3)) and store coalesced
#pragma unroll
    for (int i = 0; i < 8; ++i) {
      const int rowl = 4 * i + (lane >> 4);     // 0..31
      const int c0 = (lane & 15) * 4;
      const f32x4 v = *(const f32x4*)&wls[rowl * 64 + (c0 ^ ((i & 3) * 16))];
      const long rowg = crow0 + p * 32 + rowl;
      *(f32x4*)&C[rowg * Ndim + ccol0 + c0] = v;
    }
  }
}

extern "C" void kernel_launch(void* const* d_in, const int* in_sizes, int n_in,
                              void* d_out, int out_size, void* d_ws, size_t ws_size,
                              hipStream_t stream) {
  const float* x    = (const float*)d_in[0];
  const float* w    = (const float*)d_in[1];
  const float* bias = (const float*)d_in[2];
  float* out = (float*)d_out;

  const size_t xb_bytes = (size_t)Mdim * Kdim;
  const size_t wb_bytes = (size_t)Ndim * Kdim;   // B' same size, fragment-major
  const size_t off_X  = xb_bytes + wb_bytes;
  const size_t off_mu = off_X + (size_t)Mdim * 4;
  const size_t need   = off_mu + (size_t)Ndim * 4;
  if (ws_size < need) {
    fprintf(stderr, "kernel_launch: ws too small (%zu < %zu)\n", ws_size, need);
    return;
  }
  i8* xb8 = (i8*)d_ws;
  i8* wb8 = xb8 + xb_bytes;
  float* Xs = (float*)((char*)d_ws + off_X);
  float* muW = (float*)((char*)d_ws + off_mu);

  k_prep_w<<<Ndim, 512, 0, stream>>>(w, wb8, muW);
  k_prep_x<<<Mdim, 512, 0, stream>>>(x, xb8, Xs);

  // grid: 43 N-tiles x 32 M-tiles = 1376 blocks (divisible by 8 XCDs)
  k_gemm<<<(Ndim / 256) * (Mdim / 256), 512, 0, stream>>>(xb8, wb8, bias, muW, Xs, out);
}